// Round 1
// 6697.277 us; speedup vs baseline: 1.0686x; 1.0686x over previous
//
#include <hip/hip_runtime.h>

#define L_ 12
#define H_ 768
#define S_ 256
#define B_ 64
#define NH_ 12
#define HD_ 64
#define FF_ 3072
#define M_ (B_*S_)      // 16384 rows
#define QKVN (3*H_)     // 2304

using bf16x8 = __attribute__((ext_vector_type(8))) __bf16;
using floatx4 = __attribute__((ext_vector_type(4))) float;

typedef const __attribute__((address_space(1))) void* gptr_t;
typedef __attribute__((address_space(3))) void* sptr_t;

__device__ __forceinline__ void async_copy16(const void* g, void* s) {
  __builtin_amdgcn_global_load_lds((gptr_t)g, (sptr_t)s, 16, 0, 0);
}

__device__ __forceinline__ unsigned short f2bf(float f) {
  unsigned int u = __float_as_uint(f);
  u += 0x7fffu + ((u >> 16) & 1u);
  return (unsigned short)(u >> 16);
}
__device__ __forceinline__ float bf2f(unsigned short s) {
  return __uint_as_float(((unsigned int)s) << 16);
}

// branchless tanh-form GELU: tanh(y) = 1 - 2/(1+e^{2y}) (exact at +-inf)
__device__ __forceinline__ float gelu_f(float x) {
  float y = 0.7978845608f * (x + 0.044715f * x * x * x);
  float t = 1.0f - 2.0f / (1.0f + __expf(2.0f * y));
  return 0.5f * x * (1.0f + t);
}

// ---------------------------------------------------------------------------
// Weight transpose + fp32->bf16 convert: W[K,N] fp32 -> Wt[N,K] bf16
// ---------------------------------------------------------------------------
__global__ __launch_bounds__(256) void transpose_bf16_kernel(
    const float* __restrict__ W, unsigned short* __restrict__ Wt, int K, int N) {
  __shared__ unsigned short t[64][65];
  const int n0 = blockIdx.x * 64, k0 = blockIdx.y * 64;
  const int tid = threadIdx.x;
#pragma unroll
  for (int p = 0; p < 16; ++p) {
    int idx = p * 256 + tid;
    int r = idx >> 6, c = idx & 63;
    t[r][c] = f2bf(W[(size_t)(k0 + r) * N + n0 + c]);
  }
  __syncthreads();
#pragma unroll
  for (int p = 0; p < 16; ++p) {
    int idx = p * 256 + tid;
    int r = idx >> 6, c = idx & 63;
    Wt[(size_t)(n0 + r) * K + k0 + c] = t[c][r];
  }
}

// ---------------------------------------------------------------------------
// V transpose (bf16->bf16): qkv V region [s][d] -> vT[bh][d][s]
// grid = (4, 768), block = 256
// ---------------------------------------------------------------------------
__global__ __launch_bounds__(256) void v_transpose_kernel(
    const unsigned short* __restrict__ qkv, unsigned short* __restrict__ vT) {
  const int st = blockIdx.x, bh = blockIdx.y;
  const int b = bh / NH_, nh = bh % NH_;
  __shared__ unsigned short t[64][65];
  const int tid = threadIdx.x;
  const int s0 = st * 64;
  const size_t rowbase = (size_t)b * S_ * QKVN + 2 * H_ + nh * 64;
#pragma unroll
  for (int p = 0; p < 16; ++p) {
    int idx = p * 256 + tid;
    int r = idx >> 6, c = idx & 63;     // r = s-local, c = d
    t[r][c] = qkv[rowbase + (size_t)(s0 + r) * QKVN + c];
  }
  __syncthreads();
#pragma unroll
  for (int p = 0; p < 16; ++p) {
    int idx = p * 256 + tid;
    int r = idx >> 6, c = idx & 63;     // r = d, c = s-local
    vT[((size_t)bh * 64 + r) * 256 + s0 + c] = t[c][r];
  }
}

// ---------------------------------------------------------------------------
// Concat per-layer qkv bias
// ---------------------------------------------------------------------------
__global__ __launch_bounds__(256) void qkv_bias_kernel(
    const float* __restrict__ bq, const float* __restrict__ bk,
    const float* __restrict__ bv, float* __restrict__ out) {
  int i = blockIdx.x * 256 + threadIdx.x;
  if (i >= L_ * QKVN) return;
  int l = i / QKVN, j = i % QKVN;
  float v;
  if (j < H_) v = bq[l * H_ + j];
  else if (j < 2 * H_) v = bk[l * H_ + j - H_];
  else v = bv[l * H_ + j - 2 * H_];
  out[i] = v;
}

// ---------------------------------------------------------------------------
// Embedding + LayerNorm. grid = M_, block = 256
// ---------------------------------------------------------------------------
__global__ __launch_bounds__(256) void embed_ln_kernel(
    const int* __restrict__ ids, const int* __restrict__ tts,
    const float* __restrict__ wemb, const float* __restrict__ pemb,
    const float* __restrict__ temb, const float* __restrict__ lns,
    const float* __restrict__ lnb, float* __restrict__ h,
    unsigned short* __restrict__ hbf) {
  const int tk = blockIdx.x;
  const int s = tk & (S_ - 1);
  const int tid = threadIdx.x;
  const int id = ids[tk];
  const int tt = tts[tk];
  float v[3];
#pragma unroll
  for (int i = 0; i < 3; ++i) {
    int j = tid + i * 256;
    v[i] = wemb[(size_t)id * H_ + j] + pemb[(size_t)s * H_ + j] + temb[(size_t)tt * H_ + j];
  }
  float sum = v[0] + v[1] + v[2];
  float ssq = v[0] * v[0] + v[1] * v[1] + v[2] * v[2];
#pragma unroll
  for (int off = 32; off; off >>= 1) {
    sum += __shfl_down(sum, off);
    ssq += __shfl_down(ssq, off);
  }
  __shared__ float rs[4], rq[4];
  const int lane = tid & 63, wid = tid >> 6;
  if (lane == 0) { rs[wid] = sum; rq[wid] = ssq; }
  __syncthreads();
  const float S = rs[0] + rs[1] + rs[2] + rs[3];
  const float Q = rq[0] + rq[1] + rq[2] + rq[3];
  const float mean = S * (1.0f / 768.0f);
  const float var = Q * (1.0f / 768.0f) - mean * mean;
  const float r = rsqrtf(var + 1e-12f);
#pragma unroll
  for (int i = 0; i < 3; ++i) {
    int j = tid + i * 256;
    float y = (v[i] - mean) * r * lns[j] + lnb[j];
    h[(size_t)tk * H_ + j] = y;
    hbf[(size_t)tk * H_ + j] = f2bf(y);
  }
}

// ---------------------------------------------------------------------------
// Residual + LayerNorm: x = hin + delta(bf16); y = LN(x)*s+b -> hout + hbf
// ---------------------------------------------------------------------------
__global__ __launch_bounds__(256) void residual_ln_kernel(
    const float* __restrict__ hin, const unsigned short* __restrict__ delta,
    const float* __restrict__ lns, const float* __restrict__ lnb,
    float* __restrict__ hout, unsigned short* __restrict__ hbf) {
  const int row = blockIdx.x;
  const int tid = threadIdx.x;
  float v[3];
#pragma unroll
  for (int i = 0; i < 3; ++i) {
    int j = tid + i * 256;
    v[i] = hin[(size_t)row * H_ + j] + bf2f(delta[(size_t)row * H_ + j]);
  }
  float sum = v[0] + v[1] + v[2];
  float ssq = v[0] * v[0] + v[1] * v[1] + v[2] * v[2];
#pragma unroll
  for (int off = 32; off; off >>= 1) {
    sum += __shfl_down(sum, off);
    ssq += __shfl_down(ssq, off);
  }
  __shared__ float rs[4], rq[4];
  const int lane = tid & 63, wid = tid >> 6;
  if (lane == 0) { rs[wid] = sum; rq[wid] = ssq; }
  __syncthreads();
  const float S = rs[0] + rs[1] + rs[2] + rs[3];
  const float Q = rq[0] + rq[1] + rq[2] + rq[3];
  const float mean = S * (1.0f / 768.0f);
  const float var = Q * (1.0f / 768.0f) - mean * mean;
  const float r = rsqrtf(var + 1e-12f);
#pragma unroll
  for (int i = 0; i < 3; ++i) {
    int j = tid + i * 256;
    float y = (v[i] - mean) * r * lns[j] + lnb[j];
    hout[(size_t)row * H_ + j] = y;
    hbf[(size_t)row * H_ + j] = f2bf(y);
  }
}

// ---------------------------------------------------------------------------
// 256x256 deep-pipelined GEMM: C[M,N] = A[M,K](bf16) x Bt[N,K](bf16)^T + bias
// 512 threads = 8 waves (2M x 4N), per-wave output 128x64 (8x4 16x16 frags).
// K sliced into BK=32 tiles; LDS = 4-deep ring per operand (4 x 256x32 bf16
// = 64KB each, 128KB total, 1 block/CU).
//
// Schedule (2 phases per K-tile t, slot = t%4):
//   sub0: ds_read A frags i=0..3 + B frags j=0..3 (8 x ds_read_b128, 64B row
//         stride -> uniform 8 lanes/bank-group = conflict-free, no swizzle);
//         stage A of tile t+3 (2 x global_load_lds dwordx4);
//         s_barrier; lgkmcnt(0); setprio(1); 16 MFMA; setprio(0); s_barrier.
//   sub1: ds_read A frags i=4..7 (B regs reused); stage B of tile t+3;
//         s_waitcnt vmcnt(8)  <- counted, never 0 in main loop: retires
//         exactly through tile t+1's 4 loads (tiles t+2,t+3 stay in flight);
//         s_barrier; lgkmcnt(0); setprio(1); 16 MFMA; setprio(0); s_barrier.
// Race-freedom: slot (t+3)%4's previous tenant (tile t-1) is last ds_read in
// tile t-1 sub1 (A) / sub0 (B); the end-of-phase barriers strictly precede
// the re-stage issues in tile t sub0/sub1. Epilogue drains vmcnt 8->4->0.
// Prologue stages tiles 0..2 (12 loads), vmcnt(8) completes tile 0.
// Requires K%32==0 and K/32 >= 4 (all call sites: K=768 or 3072).
// ---------------------------------------------------------------------------
enum { EPI_BF16 = 0, EPI_GELU = 1, EPI_F32 = 2 };

#define BAR() asm volatile("s_barrier" ::: "memory")
#define WAIT_LGKM0() do { asm volatile("s_waitcnt lgkmcnt(0)" ::: "memory"); \
                          __builtin_amdgcn_sched_barrier(0); } while (0)
#define VM_WAIT(n) asm volatile("s_waitcnt vmcnt(" #n ")" ::: "memory")

#define GEMM_TILE(T_, DOSTAGE_, VMASM_)                                        \
  {                                                                            \
    const int slot_ = (T_) & 3;                                                \
    const unsigned short* Ab_ = &AS[slot_ * 8192] + aoff;                      \
    const unsigned short* Bb_ = &BS[slot_ * 8192] + boff;                      \
    bf16x8 af_[4], bf_[4];                                                     \
    _Pragma("unroll") for (int i_ = 0; i_ < 4; ++i_)                           \
        af_[i_] = *(const bf16x8*)(Ab_ + i_ * 512);                            \
    _Pragma("unroll") for (int j_ = 0; j_ < 4; ++j_)                           \
        bf_[j_] = *(const bf16x8*)(Bb_ + j_ * 512);                            \
    if (DOSTAGE_) {                                                            \
      const int ns_ = ((T_) + 3) & 3;                                          \
      const unsigned short* g_ = agp + (size_t)((T_) + 3) * 32;                \
      async_copy16(g_, asw + ns_ * 8192);                                      \
      async_copy16(g_ + (size_t)128 * K, asw + ns_ * 8192 + 4096);             \
    }                                                                          \
    BAR();                                                                     \
    WAIT_LGKM0();                                                              \
    __builtin_amdgcn_s_setprio(1);                                             \
    _Pragma("unroll") for (int i_ = 0; i_ < 4; ++i_)                           \
      _Pragma("unroll") for (int j_ = 0; j_ < 4; ++j_)                         \
        acc[i_][j_] = __builtin_amdgcn_mfma_f32_16x16x32_bf16(                 \
            bf_[j_], af_[i_], acc[i_][j_], 0, 0, 0);                           \
    __builtin_amdgcn_s_setprio(0);                                             \
    BAR();                                                                     \
    _Pragma("unroll") for (int i_ = 0; i_ < 4; ++i_)                           \
        af_[i_] = *(const bf16x8*)(Ab_ + 2048 + i_ * 512);                     \
    if (DOSTAGE_) {                                                            \
      const int ns_ = ((T_) + 3) & 3;                                          \
      const unsigned short* g_ = bgp + (size_t)((T_) + 3) * 32;                \
      async_copy16(g_, bsw + ns_ * 8192);                                      \
      async_copy16(g_ + (size_t)128 * K, bsw + ns_ * 8192 + 4096);             \
    }                                                                          \
    VMASM_;                                                                    \
    BAR();                                                                     \
    WAIT_LGKM0();                                                              \
    __builtin_amdgcn_s_setprio(1);                                             \
    _Pragma("unroll") for (int i_ = 0; i_ < 4; ++i_)                           \
      _Pragma("unroll") for (int j_ = 0; j_ < 4; ++j_)                         \
        acc[4 + i_][j_] = __builtin_amdgcn_mfma_f32_16x16x32_bf16(             \
            bf_[j_], af_[i_], acc[4 + i_][j_], 0, 0, 0);                       \
    __builtin_amdgcn_s_setprio(0);                                             \
    BAR();                                                                     \
  }

template <int EPI>
__global__ __launch_bounds__(512, 2) void gemm256_kernel(
    const unsigned short* __restrict__ A, const unsigned short* __restrict__ Bt,
    const float* __restrict__ bias, void* __restrict__ Cv,
    int M, int N, int K) {
  __shared__ __align__(128) unsigned short AS[4 * 8192];  // 4 x [256 rows][32]
  __shared__ __align__(128) unsigned short BS[4 * 8192];
  (void)M;
  const int NT = K >> 5;

  // XCD-aware bijective block swizzle (nwg % 8 == 0 at all call sites).
  const int nwg = (int)gridDim.x;
  const int nbx = N >> 8;
  const int cpx = nwg >> 3;
  const int bid = (int)blockIdx.x;
  const int swz = (bid & 7) * cpx + (bid >> 3);
  const int n0 = (swz % nbx) << 8;
  const int m0 = (swz / nbx) << 8;

  const int tid = threadIdx.x;
  const int wave = tid >> 6;
  const int lane = tid & 63;
  const int lr = lane & 15;
  const int quad = lane >> 4;
  const int wgm = wave & 1;        // M half: rows [wgm*128, wgm*128+128)
  const int wgn = wave >> 1;       // N quarter: rows [wgn*64, wgn*64+64)

  // Per-lane fragment read offsets (ushort units; row stride 32 = 64B).
  const int aoff = (wgm * 128 + lr) * 32 + quad * 8;
  const int boff = (wgn * 64 + lr) * 32 + quad * 8;

  // Staging: thread covers 16B of row (wave*16 + lane/4), cols (lane&3)*8..+7.
  // Round 0 = rows 0..127, round 1 = rows 128..255 (+128*K in global).
  const unsigned short* __restrict__ agp =
      A + (size_t)(m0 + wave * 16 + (lane >> 2)) * K + (lane & 3) * 8;
  const unsigned short* __restrict__ bgp =
      Bt + (size_t)(n0 + wave * 16 + (lane >> 2)) * K + (lane & 3) * 8;
  // LDS dest is wave-uniform (HW adds lane*16 itself).
  unsigned short* asw = &AS[wave * 512];
  unsigned short* bsw = &BS[wave * 512];

  floatx4 acc[8][4] = {};

  // Prologue: stage tiles 0..2 (order per tile: A0,A1,B0,B1 = 4 loads).
#pragma unroll
  for (int u = 0; u < 3; ++u) {
    const unsigned short* ga = agp + (size_t)u * 32;
    const unsigned short* gb = bgp + (size_t)u * 32;
    async_copy16(ga, asw + u * 8192);
    async_copy16(ga + (size_t)128 * K, asw + u * 8192 + 4096);
    async_copy16(gb, bsw + u * 8192);
    async_copy16(gb + (size_t)128 * K, bsw + u * 8192 + 4096);
  }
  VM_WAIT(8);   // tile 0 complete; tiles 1,2 in flight
  BAR();

  for (int t = 0; t < NT - 3; ++t) GEMM_TILE(t, true, VM_WAIT(8));
  GEMM_TILE(NT - 3, false, VM_WAIT(4));
  GEMM_TILE(NT - 2, false, VM_WAIT(0));
  GEMM_TILE(NT - 1, false, (void)0);

  // Epilogue: n = n0 + wgn*64 + j*16 + quad*4 + r ; m = m0 + wgm*128 + i*16 + lr
#pragma unroll
  for (int j = 0; j < 4; ++j) {
    const int nb = n0 + wgn * 64 + j * 16 + quad * 4;
    const float4 bv = *(const float4*)&bias[nb];
#pragma unroll
    for (int i = 0; i < 8; ++i) {
      const int m = m0 + wgm * 128 + i * 16 + lr;
      float v0 = acc[i][j][0] + bv.x;
      float v1 = acc[i][j][1] + bv.y;
      float v2 = acc[i][j][2] + bv.z;
      float v3 = acc[i][j][3] + bv.w;
      if (EPI == EPI_GELU) {
        v0 = gelu_f(v0); v1 = gelu_f(v1); v2 = gelu_f(v2); v3 = gelu_f(v3);
      }
      if (EPI == EPI_F32) {
        float4 o = make_float4(v0, v1, v2, v3);
        *(float4*)&((float*)Cv)[(size_t)m * N + nb] = o;
      } else {
        uint2 o;
        o.x = (unsigned)f2bf(v0) | ((unsigned)f2bf(v1) << 16);
        o.y = (unsigned)f2bf(v2) | ((unsigned)f2bf(v3) << 16);
        *(uint2*)&((unsigned short*)Cv)[(size_t)m * N + nb] = o;
      }
    }
  }
}

// ---------------------------------------------------------------------------
// MFMA flash attention. One (b,head) per block, 4 waves, wave owns 64 Q rows.
// ---------------------------------------------------------------------------
__global__ __launch_bounds__(256, 2) void flash_attn_kernel(
    const unsigned short* __restrict__ qkv, const unsigned short* __restrict__ vT,
    const int* __restrict__ mask, unsigned short* __restrict__ ctx) {
  const int bh = blockIdx.x;
  const int b = bh / NH_, nh = bh % NH_;
  __shared__ __align__(16) unsigned short Ks[64 * 64];    // [key][d]
  __shared__ __align__(16) unsigned short Vs[64 * 64];    // [d][key] (V^T tile)
  __shared__ __align__(16) unsigned short Ps[4][64 * 66]; // per-wave P [q][key]
  __shared__ float bias_s[256];
  const int tid = threadIdx.x;
  const int wave = tid >> 6, lane = tid & 63;
  const int lr = lane & 15, quad = lane >> 4;
  bias_s[tid] = (1.0f - (float)mask[b * S_ + tid]) * -10000.0f;

  const size_t rowbase = (size_t)b * S_ * QKVN;
  const int q0 = wave * 64;

  bf16x8 qf[4][2];
#pragma unroll
  for (int i = 0; i < 4; ++i)
#pragma unroll
    for (int kc = 0; kc < 2; ++kc)
      qf[i][kc] = *(const bf16x8*)&qkv[rowbase + (size_t)(q0 + i * 16 + lr) * QKVN +
                                       nh * 64 + kc * 32 + quad * 8];

  floatx4 o[4][4] = {};
  float mrow[4][4], lrow[4][4];
#pragma unroll
  for (int i = 0; i < 4; ++i)
#pragma unroll
    for (int r = 0; r < 4; ++r) { mrow[i][r] = -1e30f; lrow[i][r] = 0.f; }

  const size_t vbase = (size_t)bh * 64 * 256;

  for (int jt = 0; jt < S_; jt += 64) {
    __syncthreads();
#pragma unroll
    for (int p = 0; p < 2; ++p) {
      int cid = p * 256 + wave * 64 + lane;
      int row = cid >> 3, c = cid & 7;
      async_copy16(&qkv[rowbase + (size_t)(jt + row) * QKVN + H_ + nh * 64 + c * 8],
                   &Ks[(p * 256 + wave * 64) * 8]);
      async_copy16(&vT[vbase + (size_t)row * 256 + jt + c * 8],
                   &Vs[(p * 256 + wave * 64) * 8]);
    }
    __syncthreads();

    floatx4 s[4][4];
#pragma unroll
    for (int jn = 0; jn < 4; ++jn) {
      bf16x8 kf0 = *(const bf16x8*)&Ks[(jn * 16 + lr) * 64 + quad * 8];
      bf16x8 kf1 = *(const bf16x8*)&Ks[(jn * 16 + lr) * 64 + 32 + quad * 8];
#pragma unroll
      for (int i = 0; i < 4; ++i) {
        floatx4 a = {};
        a = __builtin_amdgcn_mfma_f32_16x16x32_bf16(qf[i][0], kf0, a, 0, 0, 0);
        a = __builtin_amdgcn_mfma_f32_16x16x32_bf16(qf[i][1], kf1, a, 0, 0, 0);
        s[i][jn] = a;
      }
    }
    float bj[4];
#pragma unroll
    for (int jn = 0; jn < 4; ++jn) bj[jn] = bias_s[jt + jn * 16 + lr];
#pragma unroll
    for (int i = 0; i < 4; ++i)
#pragma unroll
      for (int jn = 0; jn < 4; ++jn)
#pragma unroll
        for (int r = 0; r < 4; ++r)
          s[i][jn][r] = s[i][jn][r] * 0.125f + bj[jn];

#pragma unroll
    for (int i = 0; i < 4; ++i) {
#pragma unroll
      for (int r = 0; r < 4; ++r) {
        float mx = fmaxf(fmaxf(s[i][0][r], s[i][1][r]), fmaxf(s[i][2][r], s[i][3][r]));
        mx = fmaxf(mx, __shfl_xor(mx, 1));
        mx = fmaxf(mx, __shfl_xor(mx, 2));
        mx = fmaxf(mx, __shfl_xor(mx, 4));
        mx = fmaxf(mx, __shfl_xor(mx, 8));
        float mn = fmaxf(mrow[i][r], mx);
        float alpha = __expf(mrow[i][r] - mn);
        mrow[i][r] = mn;
        float ps = 0.f;
#pragma unroll
        for (int jn = 0; jn < 4; ++jn) {
          float pv = __expf(s[i][jn][r] - mn);
          s[i][jn][r] = pv;
          ps += pv;
        }
        ps += __shfl_xor(ps, 1);
        ps += __shfl_xor(ps, 2);
        ps += __shfl_xor(ps, 4);
        ps += __shfl_xor(ps, 8);
        lrow[i][r] = lrow[i][r] * alpha + ps;
#pragma unroll
        for (int n = 0; n < 4; ++n) o[i][n][r] *= alpha;
      }
    }

#pragma unroll
    for (int i = 0; i < 4; ++i)
#pragma unroll
      for (int jn = 0; jn < 4; ++jn)
#pragma unroll
        for (int r = 0; r < 4; ++r)
          Ps[wave][(i * 16 + quad * 4 + r) * 66 + jn * 16 + lr] = f2bf(s[i][jn][r]);
    __syncthreads();

#pragma unroll
    for (int kc = 0; kc < 2; ++kc) {
      bf16x8 pf[4], vf[4];
#pragma unroll
      for (int i = 0; i < 4; ++i)
        pf[i] = *(const bf16x8*)&Ps[wave][(i * 16 + lr) * 66 + kc * 32 + quad * 8];
#pragma unroll
      for (int n = 0; n < 4; ++n)
        vf[n] = *(const bf16x8*)&Vs[(n * 16 + lr) * 64 + kc * 32 + quad * 8];
#pragma unroll
      for (int i = 0; i < 4; ++i)
#pragma unroll
        for (int n = 0; n < 4; ++n)
          o[i][n] = __builtin_amdgcn_mfma_f32_16x16x32_bf16(pf[i], vf[n], o[i][n], 0, 0, 0);
    }
  }

#pragma unroll
  for (int i = 0; i < 4; ++i) {
#pragma unroll
    for (int r = 0; r < 4; ++r) {
      float inv = 1.0f / lrow[i][r];
      int row = b * S_ + q0 + i * 16 + quad * 4 + r;
#pragma unroll
      for (int n = 0; n < 4; ++n)
        ctx[(size_t)row * H_ + nh * 64 + n * 16 + lr] = f2bf(o[i][n][r] * inv);
    }
  }
}

// ---------------------------------------------------------------------------
// Head
// ---------------------------------------------------------------------------
__global__ __launch_bounds__(256) void head_kernel(
    const float* __restrict__ h, const int* __restrict__ aidx,
    const float* __restrict__ hW, const float* __restrict__ hb,
    float* __restrict__ out) {
  const int b = blockIdx.x;
  const int a = aidx[b];
  const float* cls = h + (size_t)b * S_ * H_;
  const float* w = hW + (size_t)a * H_ * 2;
  float a0 = 0.f, a1 = 0.f;
  for (int j = threadIdx.x; j < H_; j += 256) {
    float c = cls[j];
    a0 += c * w[j * 2];
    a1 += c * w[j * 2 + 1];
  }
#pragma unroll
  for (int off = 32; off; off >>= 1) {
    a0 += __shfl_down(a0, off);
    a1 += __shfl_down(a1, off);
  }
  __shared__ float r0[4], r1[4];
  const int lane = threadIdx.x & 63, wid = threadIdx.x >> 6;
  if (lane == 0) { r0[wid] = a0; r1[wid] = a1; }
  __syncthreads();
  if (threadIdx.x == 0) {
    out[b * 2 + 0] = r0[0] + r0[1] + r0[2] + r0[3] + hb[a * 2 + 0];
    out[b * 2 + 1] = r1[0] + r1[1] + r1[2] + r1[3] + hb[a * 2 + 1];
  }
}

// ---------------------------------------------------------------------------
extern "C" void kernel_launch(void* const* d_in, const int* in_sizes, int n_in,
                              void* d_out, int out_size, void* d_ws, size_t ws_size,
                              hipStream_t stream) {
  const int* input_ids = (const int*)d_in[0];
  const int* attn_mask = (const int*)d_in[1];
  const int* type_ids = (const int*)d_in[2];
  const int* aidx = (const int*)d_in[3];
  const float* wemb = (const float*)d_in[4];
  const float* pemb = (const float*)d_in[5];
  const float* temb = (const float*)d_in[6];
  const float* elns = (const float*)d_in[7];
  const float* elnb = (const float*)d_in[8];
  const float* Wq = (const float*)d_in[9];
  const float* bq = (const float*)d_in[10];
  const float* Wk = (const float*)d_in[11];
  const float* bk = (const float*)d_in[12];
  const float* Wv = (const float*)d_in[13];
  const float* bv = (const float*)d_in[14];
  const float* Wo = (const float*)d_in[15];
  const float* bo = (const float*)d_in[16];
  const float* ln1s = (const float*)d_in[17];
  const float* ln1b = (const float*)d_in[18];
  const float* W1 = (const float*)d_in[19];
  const float* b1 = (const float*)d_in[20];
  const float* W2 = (const float*)d_in[21];
  const float* b2 = (const float*)d_in[22];
  const float* ln2s = (const float*)d_in[23];
  const float* ln2b = (const float*)d_in[24];
  const float* hW = (const float*)d_in[25];
  const float* hb = (const float*)d_in[26];
  float* out = (float*)d_out;
  (void)in_sizes; (void)n_in; (void)out_size; (void)ws_size;

  char* p = (char*)d_ws;
  float* h = (float*)p;              p += (size_t)M_ * H_ * 4;
  unsigned short* delta = (unsigned short*)p;  p += (size_t)M_ * H_ * 4; // bf16, slot kept fp32-sized
  unsigned short* hbf = (unsigned short*)p;   p += (size_t)M_ * H_ * 2;
  unsigned short* qkv = (unsigned short*)p;   p += (size_t)M_ * QKVN * 2;
  unsigned short* ctx = (unsigned short*)p;   p += (size_t)M_ * H_ * 2;
  unsigned short* ffn1 = qkv;  // alias: qkv(72MB)+ctx(24MB) == 16384*3072*2
  unsigned short* wbuf = (unsigned short*)p;  p += (size_t)7077888 * 2;
  float* qkvbias = (float*)p;        p += (size_t)L_ * QKVN * 4;
  // vT aliases delta slot: vT live v_transpose->flash_attn; delta live
  // attn-out GEMM->ln1 / ffn2->ln2. Disjoint lifetimes.
  unsigned short* vT = delta;

  unsigned short* Wqkv_t = wbuf;                       // [2304, 768]
  unsigned short* Wo_t = wbuf + (size_t)QKVN * H_;     // [768, 768]
  unsigned short* W1_t = Wo_t + (size_t)H_ * H_;       // [3072, 768]
  unsigned short* W2_t = W1_t + (size_t)H_ * FF_;      // [768, 3072]

  qkv_bias_kernel<<<(L_ * QKVN + 255) / 256, 256, 0, stream>>>(bq, bk, bv, qkvbias);
  embed_ln_kernel<<<M_, 256, 0, stream>>>(input_ids, type_ids, wemb, pemb, temb,
                                          elns, elnb, h, hbf);

  for (int l = 0; l < L_; ++l) {
    const size_t HH = (size_t)H_ * H_;
    const size_t HF = (size_t)H_ * FF_;
    transpose_bf16_kernel<<<dim3(12, 12), 256, 0, stream>>>(Wq + l * HH, Wqkv_t, H_, H_);
    transpose_bf16_kernel<<<dim3(12, 12), 256, 0, stream>>>(Wk + l * HH, Wqkv_t + HH, H_, H_);
    transpose_bf16_kernel<<<dim3(12, 12), 256, 0, stream>>>(Wv + l * HH, Wqkv_t + 2 * HH, H_, H_);
    transpose_bf16_kernel<<<dim3(12, 12), 256, 0, stream>>>(Wo + l * HH, Wo_t, H_, H_);
    transpose_bf16_kernel<<<dim3(48, 12), 256, 0, stream>>>(W1 + l * HF, W1_t, H_, FF_);
    transpose_bf16_kernel<<<dim3(12, 48), 256, 0, stream>>>(W2 + l * HF, W2_t, FF_, H_);

    gemm256_kernel<EPI_BF16><<<dim3((QKVN / 256) * (M_ / 256)), 512, 0, stream>>>(
        hbf, Wqkv_t, qkvbias + (size_t)l * QKVN, qkv, M_, QKVN, H_);
    v_transpose_kernel<<<dim3(4, B_ * NH_), 256, 0, stream>>>(qkv, vT);
    flash_attn_kernel<<<B_ * NH_, 256, 0, stream>>>(qkv, vT, attn_mask, ctx);
    gemm256_kernel<EPI_BF16><<<dim3((H_ / 256) * (M_ / 256)), 512, 0, stream>>>(
        ctx, Wo_t, bo + (size_t)l * H_, delta, M_, H_, H_);
    residual_ln_kernel<<<M_, 256, 0, stream>>>(h, delta, ln1s + (size_t)l * H_,
                                               ln1b + (size_t)l * H_, h, hbf);
    gemm256_kernel<EPI_GELU><<<dim3((FF_ / 256) * (M_ / 256)), 512, 0, stream>>>(
        hbf, W1_t, b1 + (size_t)l * FF_, ffn1, M_, FF_, H_);
    gemm256_kernel<EPI_BF16><<<dim3((H_ / 256) * (M_ / 256)), 512, 0, stream>>>(
        ffn1, W2_t, b2 + (size_t)l * H_, delta, M_, H_, FF_);
    residual_ln_kernel<<<M_, 256, 0, stream>>>(h, delta, ln2s + (size_t)l * H_,
                                               ln2b + (size_t)l * H_, h, hbf);
  }

  head_kernel<<<B_, 256, 0, stream>>>(h, aidx, hW, hb, out);
}

// Round 2
// 5829.993 us; speedup vs baseline: 1.2276x; 1.1488x over previous
//
#include <hip/hip_runtime.h>

#define L_ 12
#define H_ 768
#define S_ 256
#define B_ 64
#define NH_ 12
#define HD_ 64
#define FF_ 3072
#define M_ (B_*S_)      // 16384 rows
#define QKVN (3*H_)     // 2304

using bf16x8 = __attribute__((ext_vector_type(8))) __bf16;
using floatx4 = __attribute__((ext_vector_type(4))) float;

typedef const __attribute__((address_space(1))) void* gptr_t;
typedef __attribute__((address_space(3))) void* sptr_t;

__device__ __forceinline__ void async_copy16(const void* g, void* s) {
  __builtin_amdgcn_global_load_lds((gptr_t)g, (sptr_t)s, 16, 0, 0);
}

__device__ __forceinline__ unsigned short f2bf(float f) {
  unsigned int u = __float_as_uint(f);
  u += 0x7fffu + ((u >> 16) & 1u);
  return (unsigned short)(u >> 16);
}
__device__ __forceinline__ float bf2f(unsigned short s) {
  return __uint_as_float(((unsigned int)s) << 16);
}

// branchless tanh-form GELU: tanh(y) = 1 - 2/(1+e^{2y}) (exact at +-inf)
__device__ __forceinline__ float gelu_f(float x) {
  float y = 0.7978845608f * (x + 0.044715f * x * x * x);
  float t = 1.0f - 2.0f / (1.0f + __expf(2.0f * y));
  return 0.5f * x * (1.0f + t);
}

// ---------------------------------------------------------------------------
// Weight transpose + fp32->bf16 convert: W[K,N] fp32 -> Wt[N,K] bf16
// ---------------------------------------------------------------------------
__global__ __launch_bounds__(256) void transpose_bf16_kernel(
    const float* __restrict__ W, unsigned short* __restrict__ Wt, int K, int N) {
  __shared__ unsigned short t[64][65];
  const int n0 = blockIdx.x * 64, k0 = blockIdx.y * 64;
  const int tid = threadIdx.x;
#pragma unroll
  for (int p = 0; p < 16; ++p) {
    int idx = p * 256 + tid;
    int r = idx >> 6, c = idx & 63;
    t[r][c] = f2bf(W[(size_t)(k0 + r) * N + n0 + c]);
  }
  __syncthreads();
#pragma unroll
  for (int p = 0; p < 16; ++p) {
    int idx = p * 256 + tid;
    int r = idx >> 6, c = idx & 63;
    Wt[(size_t)(n0 + r) * K + k0 + c] = t[c][r];
  }
}

// ---------------------------------------------------------------------------
// V transpose (bf16->bf16): qkv V region [s][d] -> vT[bh][d][s]
// grid = (4, 768), block = 256
// ---------------------------------------------------------------------------
__global__ __launch_bounds__(256) void v_transpose_kernel(
    const unsigned short* __restrict__ qkv, unsigned short* __restrict__ vT) {
  const int st = blockIdx.x, bh = blockIdx.y;
  const int b = bh / NH_, nh = bh % NH_;
  __shared__ unsigned short t[64][65];
  const int tid = threadIdx.x;
  const int s0 = st * 64;
  const size_t rowbase = (size_t)b * S_ * QKVN + 2 * H_ + nh * 64;
#pragma unroll
  for (int p = 0; p < 16; ++p) {
    int idx = p * 256 + tid;
    int r = idx >> 6, c = idx & 63;     // r = s-local, c = d
    t[r][c] = qkv[rowbase + (size_t)(s0 + r) * QKVN + c];
  }
  __syncthreads();
#pragma unroll
  for (int p = 0; p < 16; ++p) {
    int idx = p * 256 + tid;
    int r = idx >> 6, c = idx & 63;     // r = d, c = s-local
    vT[((size_t)bh * 64 + r) * 256 + s0 + c] = t[c][r];
  }
}

// ---------------------------------------------------------------------------
// Concat per-layer qkv bias
// ---------------------------------------------------------------------------
__global__ __launch_bounds__(256) void qkv_bias_kernel(
    const float* __restrict__ bq, const float* __restrict__ bk,
    const float* __restrict__ bv, float* __restrict__ out) {
  int i = blockIdx.x * 256 + threadIdx.x;
  if (i >= L_ * QKVN) return;
  int l = i / QKVN, j = i % QKVN;
  float v;
  if (j < H_) v = bq[l * H_ + j];
  else if (j < 2 * H_) v = bk[l * H_ + j - H_];
  else v = bv[l * H_ + j - 2 * H_];
  out[i] = v;
}

// ---------------------------------------------------------------------------
// Embedding + LayerNorm. grid = M_, block = 256
// ---------------------------------------------------------------------------
__global__ __launch_bounds__(256) void embed_ln_kernel(
    const int* __restrict__ ids, const int* __restrict__ tts,
    const float* __restrict__ wemb, const float* __restrict__ pemb,
    const float* __restrict__ temb, const float* __restrict__ lns,
    const float* __restrict__ lnb, float* __restrict__ h,
    unsigned short* __restrict__ hbf) {
  const int tk = blockIdx.x;
  const int s = tk & (S_ - 1);
  const int tid = threadIdx.x;
  const int id = ids[tk];
  const int tt = tts[tk];
  float v[3];
#pragma unroll
  for (int i = 0; i < 3; ++i) {
    int j = tid + i * 256;
    v[i] = wemb[(size_t)id * H_ + j] + pemb[(size_t)s * H_ + j] + temb[(size_t)tt * H_ + j];
  }
  float sum = v[0] + v[1] + v[2];
  float ssq = v[0] * v[0] + v[1] * v[1] + v[2] * v[2];
#pragma unroll
  for (int off = 32; off; off >>= 1) {
    sum += __shfl_down(sum, off);
    ssq += __shfl_down(ssq, off);
  }
  __shared__ float rs[4], rq[4];
  const int lane = tid & 63, wid = tid >> 6;
  if (lane == 0) { rs[wid] = sum; rq[wid] = ssq; }
  __syncthreads();
  const float S = rs[0] + rs[1] + rs[2] + rs[3];
  const float Q = rq[0] + rq[1] + rq[2] + rq[3];
  const float mean = S * (1.0f / 768.0f);
  const float var = Q * (1.0f / 768.0f) - mean * mean;
  const float r = rsqrtf(var + 1e-12f);
#pragma unroll
  for (int i = 0; i < 3; ++i) {
    int j = tid + i * 256;
    float y = (v[i] - mean) * r * lns[j] + lnb[j];
    h[(size_t)tk * H_ + j] = y;
    hbf[(size_t)tk * H_ + j] = f2bf(y);
  }
}

// ---------------------------------------------------------------------------
// Residual + LayerNorm: x = hin + delta(bf16); y = LN(x)*s+b -> hout + hbf
// ---------------------------------------------------------------------------
__global__ __launch_bounds__(256) void residual_ln_kernel(
    const float* __restrict__ hin, const unsigned short* __restrict__ delta,
    const float* __restrict__ lns, const float* __restrict__ lnb,
    float* __restrict__ hout, unsigned short* __restrict__ hbf) {
  const int row = blockIdx.x;
  const int tid = threadIdx.x;
  float v[3];
#pragma unroll
  for (int i = 0; i < 3; ++i) {
    int j = tid + i * 256;
    v[i] = hin[(size_t)row * H_ + j] + bf2f(delta[(size_t)row * H_ + j]);
  }
  float sum = v[0] + v[1] + v[2];
  float ssq = v[0] * v[0] + v[1] * v[1] + v[2] * v[2];
#pragma unroll
  for (int off = 32; off; off >>= 1) {
    sum += __shfl_down(sum, off);
    ssq += __shfl_down(ssq, off);
  }
  __shared__ float rs[4], rq[4];
  const int lane = tid & 63, wid = tid >> 6;
  if (lane == 0) { rs[wid] = sum; rq[wid] = ssq; }
  __syncthreads();
  const float S = rs[0] + rs[1] + rs[2] + rs[3];
  const float Q = rq[0] + rq[1] + rq[2] + rq[3];
  const float mean = S * (1.0f / 768.0f);
  const float var = Q * (1.0f / 768.0f) - mean * mean;
  const float r = rsqrtf(var + 1e-12f);
#pragma unroll
  for (int i = 0; i < 3; ++i) {
    int j = tid + i * 256;
    float y = (v[i] - mean) * r * lns[j] + lnb[j];
    hout[(size_t)row * H_ + j] = y;
    hbf[(size_t)row * H_ + j] = f2bf(y);
  }
}

// ---------------------------------------------------------------------------
// 128x128 pipelined GEMM: C[M,N] = A[M,K](bf16) x Bt[N,K](bf16)^T + bias[N]
// 256 threads = 4 waves (2M x 2N), wave owns 64x64 (4x4 16x16 frags,
// acc = 64 AGPR -> 3 waves/SIMD). BK=32; LDS = 3-deep ring of
// (A 128x32 + B 128x32) bf16 = 3 x 16KB = 48KB -> 3 blocks/CU.
//
// Bank-conflict-free by XOR swizzle (derived, both-sides involution):
//   LDS[row][chunk c] holds global chunk c ^ ((row>>1)&3)   (16B chunks)
//   - staging (linear DMA dest): global src col = (lane&3)^((lane>>3)&3)
//   - frag read col: quad ^= (lr>>1)&3
//   Check: half-wave (quad 0,1 x lr 0..15) hits bank-group
//   g = (lr&1)<<2 | (quad^((lr>>1)&3)) -> all 8 groups, 4 lanes each.
//
// Phase per K-tile t (slot = t mod 3):
//   ds_read af[0..3], bf[0..3] (8 x b128); stage tile t+2 -> slot (t+2)%3
//   (4 x global_load_lds); s_waitcnt vmcnt(4)  <- counted: retires tile
//   t+1's 4 loads, t+2's stay in flight; barrier; lgkmcnt(0); setprio(1);
//   16 MFMA; setprio(0); barrier.
// Race-freedom (3-deep): slot (t+2)%3's previous tenant is tile t-1; its
// reads complete (lgkm0) before tile t-1's end-barrier, which precedes
// tile t's stage issues for all waves. Tail: vmcnt(0) at t=NT-2.
// Requires K%32==0, K/32 >= 3 (call sites: K=768 or 3072).
// ---------------------------------------------------------------------------
enum { EPI_BF16 = 0, EPI_GELU = 1, EPI_F32 = 2 };

#define BAR() asm volatile("s_barrier" ::: "memory")
#define WAIT_LGKM0() do { asm volatile("s_waitcnt lgkmcnt(0)" ::: "memory"); \
                          __builtin_amdgcn_sched_barrier(0); } while (0)
#define VM_WAIT(n) asm volatile("s_waitcnt vmcnt(" #n ")" ::: "memory")

#define GEMM128_TILE(T_, SLOT_, NSLOT_, DOSTAGE_, VMASM_)                      \
  {                                                                            \
    const unsigned short* Ab_ = &AS[(SLOT_) * 4096];                           \
    const unsigned short* Bb_ = &BS[(SLOT_) * 4096];                           \
    bf16x8 af_[4], bf_[4];                                                     \
    _Pragma("unroll") for (int i_ = 0; i_ < 4; ++i_)                           \
        af_[i_] = *(const bf16x8*)(Ab_ + aoff + i_ * 512);                     \
    _Pragma("unroll") for (int j_ = 0; j_ < 4; ++j_)                           \
        bf_[j_] = *(const bf16x8*)(Bb_ + boff + j_ * 512);                     \
    if (DOSTAGE_) {                                                            \
      const unsigned short* ga_ = agp + (size_t)((T_) + 2) * 32;               \
      const unsigned short* gb_ = bgp + (size_t)((T_) + 2) * 32;               \
      _Pragma("unroll") for (int u_ = 0; u_ < 2; ++u_) {                       \
        async_copy16(ga_ + (size_t)u_ * 64 * K, asw + (NSLOT_) * 4096 + u_ * 2048); \
        async_copy16(gb_ + (size_t)u_ * 64 * K, bsw + (NSLOT_) * 4096 + u_ * 2048); \
      }                                                                        \
    }                                                                          \
    VMASM_;                                                                    \
    BAR();                                                                     \
    WAIT_LGKM0();                                                              \
    __builtin_amdgcn_s_setprio(1);                                             \
    _Pragma("unroll") for (int i_ = 0; i_ < 4; ++i_)                           \
      _Pragma("unroll") for (int j_ = 0; j_ < 4; ++j_)                         \
        acc[i_][j_] = __builtin_amdgcn_mfma_f32_16x16x32_bf16(                 \
            bf_[j_], af_[i_], acc[i_][j_], 0, 0, 0);                           \
    __builtin_amdgcn_s_setprio(0);                                             \
    BAR();                                                                     \
  }

template <int EPI>
__global__ __launch_bounds__(256, 3) void gemm128p_kernel(
    const unsigned short* __restrict__ A, const unsigned short* __restrict__ Bt,
    const float* __restrict__ bias, void* __restrict__ Cv,
    int M, int N, int K) {
  __shared__ __align__(128) unsigned short AS[3 * 4096];  // 3 x [128 rows][32]
  __shared__ __align__(128) unsigned short BS[3 * 4096];
  (void)M;
  const int NT = K >> 5;

  // XCD-aware bijective block swizzle (nwg % 8 == 0 at all call sites).
  const int nwg = (int)gridDim.x;
  const int nbx = N >> 7;
  const int cpx = nwg >> 3;
  const int bid = (int)blockIdx.x;
  const int swz = (bid & 7) * cpx + (bid >> 3);
  const int n0 = (swz % nbx) << 7;
  const int m0 = (swz / nbx) << 7;

  const int tid = threadIdx.x;
  const int wave = tid >> 6;
  const int lane = tid & 63;
  const int lr = lane & 15;
  const int quad = lane >> 4;
  const int wgm = wave & 1;        // M half: rows [wgm*64, wgm*64+64)
  const int wgn = wave >> 1;       // N half: rows [wgn*64, wgn*64+64)

  // Swizzled per-lane fragment read offsets (ushort units; row = 32 ushorts).
  const int colx = (quad ^ ((lr >> 1) & 3)) * 8;
  const int aoff = (wgm * 64 + lr) * 32 + colx;
  const int boff = (wgn * 64 + lr) * 32 + colx;

  // Staging: per copy16 a wave covers 16 rows x 64B. lane -> row wave*16 +
  // (lane>>2) (+64 for u=1), 16B chunk (lane&3) pre-permuted by ^((lane>>3)&3).
  const int srow = wave * 16 + (lane >> 2);
  const int scol = ((lane & 3) ^ ((lane >> 3) & 3)) * 8;
  const unsigned short* __restrict__ agp = A + (size_t)(m0 + srow) * K + scol;
  const unsigned short* __restrict__ bgp = Bt + (size_t)(n0 + srow) * K + scol;
  // LDS dest is wave-uniform (HW adds lane*16 itself).
  unsigned short* asw = &AS[wave * 512];
  unsigned short* bsw = &BS[wave * 512];

  floatx4 acc[4][4] = {};

  // Prologue: stage tiles 0 (slot 0) and 1 (slot 1).
#pragma unroll
  for (int t0 = 0; t0 < 2; ++t0) {
    const unsigned short* ga = agp + (size_t)t0 * 32;
    const unsigned short* gb = bgp + (size_t)t0 * 32;
#pragma unroll
    for (int u = 0; u < 2; ++u) {
      async_copy16(ga + (size_t)u * 64 * K, asw + t0 * 4096 + u * 2048);
      async_copy16(gb + (size_t)u * 64 * K, bsw + t0 * 4096 + u * 2048);
    }
  }
  VM_WAIT(4);   // tile 0 complete; tile 1 in flight
  BAR();

  int sl = 0;
  int t = 0;
  for (; t < NT - 2; ++t) {
    const int ns = (sl >= 1) ? sl - 1 : 2;   // (sl + 2) % 3
    GEMM128_TILE(t, sl, ns, true, VM_WAIT(4));
    sl = (sl == 2) ? 0 : sl + 1;
  }
  GEMM128_TILE(t, sl, 0, false, VM_WAIT(0));
  sl = (sl == 2) ? 0 : sl + 1;
  ++t;
  GEMM128_TILE(t, sl, 0, false, (void)0);

  // Epilogue: m = m0 + wgm*64 + i*16 + lr ; n = n0 + wgn*64 + j*16 + quad*4 + r
#pragma unroll
  for (int j = 0; j < 4; ++j) {
    const int nb = n0 + wgn * 64 + j * 16 + quad * 4;
    const float4 bv = *(const float4*)&bias[nb];
#pragma unroll
    for (int i = 0; i < 4; ++i) {
      const int m = m0 + wgm * 64 + i * 16 + lr;
      float v0 = acc[i][j][0] + bv.x;
      float v1 = acc[i][j][1] + bv.y;
      float v2 = acc[i][j][2] + bv.z;
      float v3 = acc[i][j][3] + bv.w;
      if (EPI == EPI_GELU) {
        v0 = gelu_f(v0); v1 = gelu_f(v1); v2 = gelu_f(v2); v3 = gelu_f(v3);
      }
      if (EPI == EPI_F32) {
        float4 o = make_float4(v0, v1, v2, v3);
        *(float4*)&((float*)Cv)[(size_t)m * N + nb] = o;
      } else {
        uint2 o;
        o.x = (unsigned)f2bf(v0) | ((unsigned)f2bf(v1) << 16);
        o.y = (unsigned)f2bf(v2) | ((unsigned)f2bf(v3) << 16);
        *(uint2*)&((unsigned short*)Cv)[(size_t)m * N + nb] = o;
      }
    }
  }
}

// ---------------------------------------------------------------------------
// MFMA flash attention. One (b,head) per block, 4 waves, wave owns 64 Q rows.
// ---------------------------------------------------------------------------
__global__ __launch_bounds__(256, 2) void flash_attn_kernel(
    const unsigned short* __restrict__ qkv, const unsigned short* __restrict__ vT,
    const int* __restrict__ mask, unsigned short* __restrict__ ctx) {
  const int bh = blockIdx.x;
  const int b = bh / NH_, nh = bh % NH_;
  __shared__ __align__(16) unsigned short Ks[64 * 64];    // [key][d]
  __shared__ __align__(16) unsigned short Vs[64 * 64];    // [d][key] (V^T tile)
  __shared__ __align__(16) unsigned short Ps[4][64 * 66]; // per-wave P [q][key]
  __shared__ float bias_s[256];
  const int tid = threadIdx.x;
  const int wave = tid >> 6, lane = tid & 63;
  const int lr = lane & 15, quad = lane >> 4;
  bias_s[tid] = (1.0f - (float)mask[b * S_ + tid]) * -10000.0f;

  const size_t rowbase = (size_t)b * S_ * QKVN;
  const int q0 = wave * 64;

  bf16x8 qf[4][2];
#pragma unroll
  for (int i = 0; i < 4; ++i)
#pragma unroll
    for (int kc = 0; kc < 2; ++kc)
      qf[i][kc] = *(const bf16x8*)&qkv[rowbase + (size_t)(q0 + i * 16 + lr) * QKVN +
                                       nh * 64 + kc * 32 + quad * 8];

  floatx4 o[4][4] = {};
  float mrow[4][4], lrow[4][4];
#pragma unroll
  for (int i = 0; i < 4; ++i)
#pragma unroll
    for (int r = 0; r < 4; ++r) { mrow[i][r] = -1e30f; lrow[i][r] = 0.f; }

  const size_t vbase = (size_t)bh * 64 * 256;

  for (int jt = 0; jt < S_; jt += 64) {
    __syncthreads();
#pragma unroll
    for (int p = 0; p < 2; ++p) {
      int cid = p * 256 + wave * 64 + lane;
      int row = cid >> 3, c = cid & 7;
      async_copy16(&qkv[rowbase + (size_t)(jt + row) * QKVN + H_ + nh * 64 + c * 8],
                   &Ks[(p * 256 + wave * 64) * 8]);
      async_copy16(&vT[vbase + (size_t)row * 256 + jt + c * 8],
                   &Vs[(p * 256 + wave * 64) * 8]);
    }
    __syncthreads();

    floatx4 s[4][4];
#pragma unroll
    for (int jn = 0; jn < 4; ++jn) {
      bf16x8 kf0 = *(const bf16x8*)&Ks[(jn * 16 + lr) * 64 + quad * 8];
      bf16x8 kf1 = *(const bf16x8*)&Ks[(jn * 16 + lr) * 64 + 32 + quad * 8];
#pragma unroll
      for (int i = 0; i < 4; ++i) {
        floatx4 a = {};
        a = __builtin_amdgcn_mfma_f32_16x16x32_bf16(qf[i][0], kf0, a, 0, 0, 0);
        a = __builtin_amdgcn_mfma_f32_16x16x32_bf16(qf[i][1], kf1, a, 0, 0, 0);
        s[i][jn] = a;
      }
    }
    float bj[4];
#pragma unroll
    for (int jn = 0; jn < 4; ++jn) bj[jn] = bias_s[jt + jn * 16 + lr];
#pragma unroll
    for (int i = 0; i < 4; ++i)
#pragma unroll
      for (int jn = 0; jn < 4; ++jn)
#pragma unroll
        for (int r = 0; r < 4; ++r)
          s[i][jn][r] = s[i][jn][r] * 0.125f + bj[jn];

#pragma unroll
    for (int i = 0; i < 4; ++i) {
#pragma unroll
      for (int r = 0; r < 4; ++r) {
        float mx = fmaxf(fmaxf(s[i][0][r], s[i][1][r]), fmaxf(s[i][2][r], s[i][3][r]));
        mx = fmaxf(mx, __shfl_xor(mx, 1));
        mx = fmaxf(mx, __shfl_xor(mx, 2));
        mx = fmaxf(mx, __shfl_xor(mx, 4));
        mx = fmaxf(mx, __shfl_xor(mx, 8));
        float mn = fmaxf(mrow[i][r], mx);
        float alpha = __expf(mrow[i][r] - mn);
        mrow[i][r] = mn;
        float ps = 0.f;
#pragma unroll
        for (int jn = 0; jn < 4; ++jn) {
          float pv = __expf(s[i][jn][r] - mn);
          s[i][jn][r] = pv;
          ps += pv;
        }
        ps += __shfl_xor(ps, 1);
        ps += __shfl_xor(ps, 2);
        ps += __shfl_xor(ps, 4);
        ps += __shfl_xor(ps, 8);
        lrow[i][r] = lrow[i][r] * alpha + ps;
#pragma unroll
        for (int n = 0; n < 4; ++n) o[i][n][r] *= alpha;
      }
    }

#pragma unroll
    for (int i = 0; i < 4; ++i)
#pragma unroll
      for (int jn = 0; jn < 4; ++jn)
#pragma unroll
        for (int r = 0; r < 4; ++r)
          Ps[wave][(i * 16 + quad * 4 + r) * 66 + jn * 16 + lr] = f2bf(s[i][jn][r]);
    __syncthreads();

#pragma unroll
    for (int kc = 0; kc < 2; ++kc) {
      bf16x8 pf[4], vf[4];
#pragma unroll
      for (int i = 0; i < 4; ++i)
        pf[i] = *(const bf16x8*)&Ps[wave][(i * 16 + lr) * 66 + kc * 32 + quad * 8];
#pragma unroll
      for (int n = 0; n < 4; ++n)
        vf[n] = *(const bf16x8*)&Vs[(n * 16 + lr) * 64 + kc * 32 + quad * 8];
#pragma unroll
      for (int i = 0; i < 4; ++i)
#pragma unroll
        for (int n = 0; n < 4; ++n)
          o[i][n] = __builtin_amdgcn_mfma_f32_16x16x32_bf16(pf[i], vf[n], o[i][n], 0, 0, 0);
    }
  }

#pragma unroll
  for (int i = 0; i < 4; ++i) {
#pragma unroll
    for (int r = 0; r < 4; ++r) {
      float inv = 1.0f / lrow[i][r];
      int row = b * S_ + q0 + i * 16 + quad * 4 + r;
#pragma unroll
      for (int n = 0; n < 4; ++n)
        ctx[(size_t)row * H_ + nh * 64 + n * 16 + lr] = f2bf(o[i][n][r] * inv);
    }
  }
}

// ---------------------------------------------------------------------------
// Head
// ---------------------------------------------------------------------------
__global__ __launch_bounds__(256) void head_kernel(
    const float* __restrict__ h, const int* __restrict__ aidx,
    const float* __restrict__ hW, const float* __restrict__ hb,
    float* __restrict__ out) {
  const int b = blockIdx.x;
  const int a = aidx[b];
  const float* cls = h + (size_t)b * S_ * H_;
  const float* w = hW + (size_t)a * H_ * 2;
  float a0 = 0.f, a1 = 0.f;
  for (int j = threadIdx.x; j < H_; j += 256) {
    float c = cls[j];
    a0 += c * w[j * 2];
    a1 += c * w[j * 2 + 1];
  }
#pragma unroll
  for (int off = 32; off; off >>= 1) {
    a0 += __shfl_down(a0, off);
    a1 += __shfl_down(a1, off);
  }
  __shared__ float r0[4], r1[4];
  const int lane = threadIdx.x & 63, wid = threadIdx.x >> 6;
  if (lane == 0) { r0[wid] = a0; r1[wid] = a1; }
  __syncthreads();
  if (threadIdx.x == 0) {
    out[b * 2 + 0] = r0[0] + r0[1] + r0[2] + r0[3] + hb[a * 2 + 0];
    out[b * 2 + 1] = r1[0] + r1[1] + r1[2] + r1[3] + hb[a * 2 + 1];
  }
}

// ---------------------------------------------------------------------------
extern "C" void kernel_launch(void* const* d_in, const int* in_sizes, int n_in,
                              void* d_out, int out_size, void* d_ws, size_t ws_size,
                              hipStream_t stream) {
  const int* input_ids = (const int*)d_in[0];
  const int* attn_mask = (const int*)d_in[1];
  const int* type_ids = (const int*)d_in[2];
  const int* aidx = (const int*)d_in[3];
  const float* wemb = (const float*)d_in[4];
  const float* pemb = (const float*)d_in[5];
  const float* temb = (const float*)d_in[6];
  const float* elns = (const float*)d_in[7];
  const float* elnb = (const float*)d_in[8];
  const float* Wq = (const float*)d_in[9];
  const float* bq = (const float*)d_in[10];
  const float* Wk = (const float*)d_in[11];
  const float* bk = (const float*)d_in[12];
  const float* Wv = (const float*)d_in[13];
  const float* bv = (const float*)d_in[14];
  const float* Wo = (const float*)d_in[15];
  const float* bo = (const float*)d_in[16];
  const float* ln1s = (const float*)d_in[17];
  const float* ln1b = (const float*)d_in[18];
  const float* W1 = (const float*)d_in[19];
  const float* b1 = (const float*)d_in[20];
  const float* W2 = (const float*)d_in[21];
  const float* b2 = (const float*)d_in[22];
  const float* ln2s = (const float*)d_in[23];
  const float* ln2b = (const float*)d_in[24];
  const float* hW = (const float*)d_in[25];
  const float* hb = (const float*)d_in[26];
  float* out = (float*)d_out;
  (void)in_sizes; (void)n_in; (void)out_size; (void)ws_size;

  char* p = (char*)d_ws;
  float* h = (float*)p;              p += (size_t)M_ * H_ * 4;
  unsigned short* delta = (unsigned short*)p;  p += (size_t)M_ * H_ * 4; // bf16, slot kept fp32-sized
  unsigned short* hbf = (unsigned short*)p;   p += (size_t)M_ * H_ * 2;
  unsigned short* qkv = (unsigned short*)p;   p += (size_t)M_ * QKVN * 2;
  unsigned short* ctx = (unsigned short*)p;   p += (size_t)M_ * H_ * 2;
  unsigned short* ffn1 = qkv;  // alias: qkv(72MB)+ctx(24MB) == 16384*3072*2
  unsigned short* wbuf = (unsigned short*)p;  p += (size_t)7077888 * 2;
  float* qkvbias = (float*)p;        p += (size_t)L_ * QKVN * 4;
  // vT aliases delta slot: vT live v_transpose->flash_attn; delta live
  // attn-out GEMM->ln1 / ffn2->ln2. Disjoint lifetimes.
  unsigned short* vT = delta;

  unsigned short* Wqkv_t = wbuf;                       // [2304, 768]
  unsigned short* Wo_t = wbuf + (size_t)QKVN * H_;     // [768, 768]
  unsigned short* W1_t = Wo_t + (size_t)H_ * H_;       // [3072, 768]
  unsigned short* W2_t = W1_t + (size_t)H_ * FF_;      // [768, 3072]

  qkv_bias_kernel<<<(L_ * QKVN + 255) / 256, 256, 0, stream>>>(bq, bk, bv, qkvbias);
  embed_ln_kernel<<<M_, 256, 0, stream>>>(input_ids, type_ids, wemb, pemb, temb,
                                          elns, elnb, h, hbf);

  for (int l = 0; l < L_; ++l) {
    const size_t HH = (size_t)H_ * H_;
    const size_t HF = (size_t)H_ * FF_;
    transpose_bf16_kernel<<<dim3(12, 12), 256, 0, stream>>>(Wq + l * HH, Wqkv_t, H_, H_);
    transpose_bf16_kernel<<<dim3(12, 12), 256, 0, stream>>>(Wk + l * HH, Wqkv_t + HH, H_, H_);
    transpose_bf16_kernel<<<dim3(12, 12), 256, 0, stream>>>(Wv + l * HH, Wqkv_t + 2 * HH, H_, H_);
    transpose_bf16_kernel<<<dim3(12, 12), 256, 0, stream>>>(Wo + l * HH, Wo_t, H_, H_);
    transpose_bf16_kernel<<<dim3(48, 12), 256, 0, stream>>>(W1 + l * HF, W1_t, H_, FF_);
    transpose_bf16_kernel<<<dim3(12, 48), 256, 0, stream>>>(W2 + l * HF, W2_t, FF_, H_);

    gemm128p_kernel<EPI_BF16><<<dim3((QKVN / 128) * (M_ / 128)), 256, 0, stream>>>(
        hbf, Wqkv_t, qkvbias + (size_t)l * QKVN, qkv, M_, QKVN, H_);
    v_transpose_kernel<<<dim3(4, B_ * NH_), 256, 0, stream>>>(qkv, vT);
    flash_attn_kernel<<<B_ * NH_, 256, 0, stream>>>(qkv, vT, attn_mask, ctx);
    gemm128p_kernel<EPI_BF16><<<dim3((H_ / 128) * (M_ / 128)), 256, 0, stream>>>(
        ctx, Wo_t, bo + (size_t)l * H_, delta, M_, H_, H_);
    residual_ln_kernel<<<M_, 256, 0, stream>>>(h, delta, ln1s + (size_t)l * H_,
                                               ln1b + (size_t)l * H_, h, hbf);
    gemm128p_kernel<EPI_GELU><<<dim3((FF_ / 128) * (M_ / 128)), 256, 0, stream>>>(
        hbf, W1_t, b1 + (size_t)l * FF_, ffn1, M_, FF_, H_);
    gemm128p_kernel<EPI_BF16><<<dim3((H_ / 128) * (M_ / 128)), 256, 0, stream>>>(
        ffn1, W2_t, b2 + (size_t)l * H_, delta, M_, H_, FF_);
    residual_ln_kernel<<<M_, 256, 0, stream>>>(h, delta, ln2s + (size_t)l * H_,
                                               ln2b + (size_t)l * H_, h, hbf);
  }

  head_kernel<<<B_, 256, 0, stream>>>(h, aidx, hW, hb, out);
}